// Round 5
// baseline (516.689 us; speedup 1.0000x reference)
//
#include <hip/hip_runtime.h>
#include <hip/hip_bf16.h>
#include <cstdint>
#include <cstddef>

typedef __bf16 bf16x8 __attribute__((ext_vector_type(8)));
typedef float floatx4 __attribute__((ext_vector_type(4)));
typedef unsigned short ushort4v __attribute__((ext_vector_type(4)));
typedef unsigned short ushort8v __attribute__((ext_vector_type(8)));

#define MFMA(a, b, c) __builtin_amdgcn_mfma_f32_16x16x32_bf16((a), (b), (c), 0, 0, 0)

__device__ __forceinline__ unsigned short f2bf(float f) {
  unsigned u = __builtin_bit_cast(unsigned, f);
  u += 0x7fffu + ((u >> 16) & 1u);
  return (unsigned short)(u >> 16);
}
__device__ __forceinline__ float bf2f(unsigned short h) {
  unsigned u = ((unsigned)h) << 16;
  return __builtin_bit_cast(float, u);
}
__device__ __forceinline__ float fast_exp2(float x) {
#if __has_builtin(__builtin_amdgcn_exp2f)
  return __builtin_amdgcn_exp2f(x);
#else
  return exp2f(x);
#endif
}

// async 16B global -> LDS DMA. LDS dest = wave-uniform base + lane*16.
__device__ __forceinline__ void gl2lds16(const unsigned short* g, unsigned short* l) {
  __builtin_amdgcn_global_load_lds(
      (const __attribute__((address_space(1))) unsigned int*)g,
      (__attribute__((address_space(3))) unsigned int*)l, 16, 0, 0);
}

// ---------------- fp32 -> bf16 convert (x) ----------------
__global__ void convert_f32_bf16(const float* __restrict__ src,
                                 unsigned short* __restrict__ dst, int n4) {
  int i = blockIdx.x * 256 + threadIdx.x;
  if (i >= n4) return;
  float4 f = ((const float4*)src)[i];
  ushort4 o;
  o.x = f2bf(f.x); o.y = f2bf(f.y); o.z = f2bf(f.z); o.w = f2bf(f.w);
  ((ushort4*)dst)[i] = o;
}

// ---------------- fp32 (K x N) -> bf16 transposed (N x K), 64x64 tiles ----------------
__global__ void transpose_f32_bf16(const float* __restrict__ src,
                                   unsigned short* __restrict__ dst, int K, int N) {
  __shared__ float tile[64 * 65];
  int tn = blockIdx.x * 64, tk = blockIdx.y * 64;
  int r = threadIdx.x >> 4;          // 0..15
  int c4 = (threadIdx.x & 15) * 4;   // 0,4,..,60
#pragma unroll
  for (int i = 0; i < 4; i++) {
    float4 f = *(const float4*)&src[(size_t)(tk + r + 16 * i) * N + tn + c4];
    float* tr = &tile[(r + 16 * i) * 65 + c4];
    tr[0] = f.x; tr[1] = f.y; tr[2] = f.z; tr[3] = f.w;
  }
  __syncthreads();
#pragma unroll
  for (int i = 0; i < 4; i++) {
    ushort4 o;
    o.x = f2bf(tile[(c4 + 0) * 65 + r + 16 * i]);
    o.y = f2bf(tile[(c4 + 1) * 65 + r + 16 * i]);
    o.z = f2bf(tile[(c4 + 2) * 65 + r + 16 * i]);
    o.w = f2bf(tile[(c4 + 3) * 65 + r + 16 * i]);
    *(ushort4*)&dst[(size_t)(tn + r + 16 * i) * K + tk + c4] = o;
  }
}

// ---------------- bf16 GEMM: C = A(MxK) * Bt(NxK)^T ----------------
// 128x128 tile, BK=64, XOR-swizzled global_load_lds staging (validated r3:
// SQ_LDS_BANK_CONFLICT=0, ~880 TF = m97-structure plateau).
template <bool F32OUT>
__global__ __launch_bounds__(256) void gemm_bt(const unsigned short* __restrict__ A,
                        const unsigned short* __restrict__ Bt,
                        void* __restrict__ C, int M, int N, int K) {
  __shared__ alignas(16) unsigned short Alds[128 * 64];
  __shared__ alignas(16) unsigned short Blds[128 * 64];
  const int tid = threadIdx.x;
  const int w = tid >> 6, L = tid & 63;
  const int lr = L & 15, lg = L >> 4;
  const int bm = blockIdx.y * 128, bn = blockIdx.x * 128;
  const int wm = (w >> 1) * 64, wn = (w & 1) * 64;
  floatx4 acc[4][4] = {};

  const int srow = L >> 3;               // 0..7
  const int pcg = L & 7;
  const int scg = (pcg ^ srow) * 8;      // source-side swizzle

  const unsigned short* Ag = &A[(size_t)(bm + w * 32 + srow) * K + scg];
  const unsigned short* Bg = &Bt[(size_t)(bn + w * 32 + srow) * K + scg];
  unsigned short* Al = &Alds[(w * 32 + srow) * 64 + pcg * 8];
  unsigned short* Bl = &Blds[(w * 32 + srow) * 64 + pcg * 8];

  for (int k0 = 0; k0 < K; k0 += 64) {
#pragma unroll
    for (int i = 0; i < 4; i++) {
      gl2lds16(Ag + (size_t)(i * 8) * K, Al + i * 8 * 64);
      gl2lds16(Bg + (size_t)(i * 8) * K, Bl + i * 8 * 64);
    }
    Ag += 64; Bg += 64;
    __syncthreads();

#pragma unroll
    for (int kk = 0; kk < 2; kk++) {
      const int ofs = ((kk * 4 + lg) ^ (lr & 7)) * 8;
      bf16x8 af[4], bfr[4];
#pragma unroll
      for (int i = 0; i < 4; i++) {
        af[i]  = *(const bf16x8*)&Alds[(wm + i * 16 + lr) * 64 + ofs];
        bfr[i] = *(const bf16x8*)&Blds[(wn + i * 16 + lr) * 64 + ofs];
      }
#pragma unroll
      for (int mi = 0; mi < 4; mi++)
#pragma unroll
        for (int ni = 0; ni < 4; ni++)
          acc[mi][ni] = MFMA(af[mi], bfr[ni], acc[mi][ni]);
    }
    __syncthreads();
  }

#pragma unroll
  for (int mi = 0; mi < 4; mi++) {
#pragma unroll
    for (int ni = 0; ni < 4; ni++) {
#pragma unroll
      for (int r = 0; r < 4; r++) {
        size_t row = bm + wm + mi * 16 + lg * 4 + r;
        size_t col = bn + wn + ni * 16 + lr;
        float v = acc[mi][ni][r];
        if constexpr (F32OUT) ((float*)C)[row * N + col] = v;
        else ((unsigned short*)C)[row * N + col] = f2bf(v);
      }
    }
  }
}

// ---------------- RoPE in place on bf16 rows, optional scale ----------------
__global__ void rope_kernel(unsigned short* __restrict__ X, const float* __restrict__ cs,
                            int H, int rowStride, int colOff, float scale) {
  int idx = blockIdx.x * 256 + threadIdx.x;
  int d = idx & 63;
  int h = (idx >> 6) % H;
  int s = idx / (64 * H);
  size_t base = (size_t)s * rowStride + colOff + (size_t)h * 128;
  float x1 = bf2f(X[base + d]), x2 = bf2f(X[base + d + 64]);
  float c = cs[s * 64 + d];
  float sn = cs[2048 * 64 + s * 64 + d];
  float y1 = (x1 * c + x2 * sn) * scale;
  float y2 = (x2 * c - x1 * sn) * scale;
  X[base + d] = f2bf(y1);
  X[base + d + 64] = f2bf(y2);
}

// ---------------- V (cols 5120.. of QKV, stride 6144) -> Vt (8,128,2048) ----------------
__global__ void v_transpose(const unsigned short* __restrict__ QKV,
                            unsigned short* __restrict__ Vt) {
  __shared__ unsigned short tile[32][33];
  int h = blockIdx.z;
  int s0 = blockIdx.x * 32, d0 = blockIdx.y * 32;
  int c = threadIdx.x & 31, r0 = threadIdx.x >> 5;
#pragma unroll
  for (int i = 0; i < 32; i += 8)
    tile[r0 + i][c] = QKV[(size_t)(s0 + r0 + i) * 6144 + 5120 + h * 128 + d0 + c];
  __syncthreads();
#pragma unroll
  for (int i = 0; i < 32; i += 8)
    Vt[(size_t)(h * 128 + d0 + r0 + i) * 2048 + s0 + c] = tile[c][r0 + i];
}

// ---------------- causal flash attention (v3) ----------------
// Block = 2 heads (same KV group) x 64 q-rows; wave w -> head hq=hk*4+hp*2+(w&1),
// q-rows [qb*64+(w>>1)*32, +32). K/V staged via swizzled global_load_lds (r4).
// NEW: QK computes S^T (A=K, B=Q) so scores land with q=lane&15; PV computes
// O^T (A=V^T from LDS, B=P built LANE-LOCALLY from score registers via the
// k-slot bijection j<4 -> kv=lg*4+j, j>=4 -> kv=16+lg*4+(j-4)). The entire P
// LDS round-trip (32 u16 writes + 4 b128 reads + ds-chain latency per tile)
// is gone; Plds removed (LDS 50->32 KB). Fixed-max exp2 softmax (r3).
__global__ __launch_bounds__(256) void flash_kernel(
    const unsigned short* __restrict__ QKV,  // (2048, 6144) roped; Q pre-scaled
    const unsigned short* __restrict__ Vt,   // (8, 128, 2048)
    unsigned short* __restrict__ O) {        // (2048, 4096)
  __shared__ alignas(16) unsigned short Klds[64 * 128];   // 16 KB, swizzled cg16
  __shared__ alignas(16) unsigned short Vlds[128 * 64];   // 16 KB, swizzled cg8
  const int tid = threadIdx.x, w = tid >> 6, L = tid & 63;
  const int lr = L & 15, lg = L >> 4;
  const int bid = blockIdx.x;
  const int hk = bid & 7;
  const int hp = (bid >> 3) & 1;
  const int qb = 31 - (bid >> 4);          // heavy blocks dispatch first
  const int hq = hk * 4 + hp * 2 + (w & 1);
  const int qr0 = qb * 64 + (w >> 1) * 32; // wave's 32 q-rows
  const unsigned short* Kg = QKV + 4096;

  // K staging: row=flat>>4, lcg=flat&15, source cg = lcg ^ (row&15)
  const int k_row = tid >> 4, k_lcg = tid & 15;
  const unsigned short* KgT = &Kg[(size_t)k_row * 6144 + hk * 128 + ((k_lcg ^ (k_row & 15)) * 8)];
  unsigned short* KlT = &Klds[k_row * 128 + k_lcg * 8];
  // V staging: row=flat>>3 (dh), lcg=flat&7, source cg = lcg ^ (row&7)
  const int v_row = tid >> 3, v_lcg = tid & 7;
  const unsigned short* VgT = &Vt[(size_t)(hk * 128 + v_row) * 2048 + ((v_lcg ^ (v_row & 7)) * 8)];
  unsigned short* VlT = &Vlds[v_row * 64 + v_lcg * 8];

  bf16x8 qf[2][4];
#pragma unroll
  for (int mi = 0; mi < 2; mi++)
#pragma unroll
    for (int cd = 0; cd < 4; cd++)
      qf[mi][cd] = *(const bf16x8*)&QKV[(size_t)(qr0 + mi * 16 + lr) * 6144 + hq * 128 + cd * 32 + lg * 8];

  floatx4 oacc[2][8] = {};
  float l_lane[2] = {0.f, 0.f};

  for (int t = 0; t <= qb; t++) {
    const int kv0 = t * 64;
    __syncthreads();  // previous tile's K/V reads done before restaging
#pragma unroll
    for (int i = 0; i < 4; i++) {
      gl2lds16(KgT + (size_t)(kv0 + i * 16) * 6144, KlT + i * 16 * 128);
      gl2lds16(VgT + kv0 + (size_t)(i * 32) * 2048, VlT + i * 32 * 64);
    }
    __syncthreads();

#pragma unroll
    for (int c = 0; c < 2; c++) {      // kv 32-chunk of the 64-tile
      floatx4 sc[2][2];                // [nt_l][mi]
#pragma unroll
      for (int ntl = 0; ntl < 2; ntl++) {
        const int nt = c * 2 + ntl;
        bf16x8 kf[4];
#pragma unroll
        for (int cd = 0; cd < 4; cd++)
          kf[cd] = *(const bf16x8*)&Klds[(nt * 16 + lr) * 128 + (((cd * 4 + lg) ^ lr) * 8)];
#pragma unroll
        for (int mi = 0; mi < 2; mi++) {
          floatx4 a = {};
#pragma unroll
          for (int cd = 0; cd < 4; cd++) a = MFMA(kf[cd], qf[mi][cd], a);
          sc[ntl][mi] = a;   // S^T: kv = kv0+nt*16+lg*4+r, q = qr0+mi*16+lr
        }
      }
      if (t == qb) {  // diagonal tile: causal mask
#pragma unroll
        for (int ntl = 0; ntl < 2; ntl++)
#pragma unroll
          for (int mi = 0; mi < 2; mi++)
#pragma unroll
            for (int r = 0; r < 4; r++)
              if (kv0 + (c * 2 + ntl) * 16 + lg * 4 + r > qr0 + mi * 16 + lr)
                sc[ntl][mi][r] = -3e38f;
      }
      // exp2, row-sum partial, lane-local pack into K=32 B-fragment:
      // slot j<4 -> kv chunk offset lg*4+j (ntl=0), j>=4 -> 16+lg*4+(j-4) (ntl=1)
      bf16x8 pb[2];
#pragma unroll
      for (int mi = 0; mi < 2; mi++) {
        ushort8v pu;
#pragma unroll
        for (int ntl = 0; ntl < 2; ntl++)
#pragma unroll
          for (int r = 0; r < 4; r++) {
            float p = fast_exp2(sc[ntl][mi][r]);
            l_lane[mi] += p;
            pu[ntl * 4 + r] = f2bf(p);
          }
        pb[mi] = __builtin_bit_cast(bf16x8, pu);
      }
      // PV chunk: A = V^T fragments (two b64 from swizzled Vlds), B = pb
#pragma unroll
      for (int n = 0; n < 8; n++) {
        const int row = (n * 16 + lr) * 64;
        ushort4v vlo = *(const ushort4v*)&Vlds[row + (((c * 4 + (lg >> 1)) ^ (lr & 7)) * 8) + (lg & 1) * 4];
        ushort4v vhi = *(const ushort4v*)&Vlds[row + (((c * 4 + 2 + (lg >> 1)) ^ (lr & 7)) * 8) + (lg & 1) * 4];
        ushort8v v8 = __builtin_shufflevector(vlo, vhi, 0, 1, 2, 3, 4, 5, 6, 7);
        bf16x8 vf = __builtin_bit_cast(bf16x8, v8);
#pragma unroll
        for (int mi = 0; mi < 2; mi++) oacc[mi][n] = MFMA(vf, pb[mi], oacc[mi][n]);
      }
    }
  }

  // full row-sum: combine the 4 lg-groups' partials (each held kv subsets)
  float linv[2];
#pragma unroll
  for (int mi = 0; mi < 2; mi++) {
    float l = l_lane[mi];
    l += __shfl_xor(l, 16);
    l += __shfl_xor(l, 32);
    linv[mi] = 1.0f / l;
  }

  // O^T C-layout: lane holds d = n*16+lg*4+r (r=0..3 consecutive cols), q = qr0+mi*16+lr
#pragma unroll
  for (int mi = 0; mi < 2; mi++)
#pragma unroll
    for (int n = 0; n < 8; n++) {
      ushort4 o;
      o.x = f2bf(oacc[mi][n][0] * linv[mi]);
      o.y = f2bf(oacc[mi][n][1] * linv[mi]);
      o.z = f2bf(oacc[mi][n][2] * linv[mi]);
      o.w = f2bf(oacc[mi][n][3] * linv[mi]);
      *(ushort4*)&O[(size_t)(qr0 + mi * 16 + lr) * 4096 + hq * 128 + n * 16 + lg * 4] = o;
    }
}

extern "C" void kernel_launch(void* const* d_in, const int* in_sizes, int n_in,
                              void* d_out, int out_size, void* d_ws, size_t ws_size,
                              hipStream_t stream) {
  const float* x  = (const float*)d_in[0];
  const float* cs = (const float*)d_in[1];
  const float* wq = (const float*)d_in[2];
  const float* wk = (const float*)d_in[3];
  const float* wv = (const float*)d_in[4];
  const float* wo = (const float*)d_in[5];
  float* out = (float*)d_out;

  char* ws = (char*)d_ws;
  unsigned short* xb   = (unsigned short*)(ws);               // 16 MB  x bf16
  unsigned short* wqt  = (unsigned short*)(ws + 16777216);    // 32 MB  wq^T } contiguous
  unsigned short* wkt  = (unsigned short*)(ws + 50331648);    // 8 MB   wk^T } B for fused
  unsigned short* wvt  = (unsigned short*)(ws + 58720256);    // 8 MB   wv^T } QKV gemm
  unsigned short* wot  = (unsigned short*)(ws + 67108864);    // 32 MB  wo^T
  unsigned short* QKVb = (unsigned short*)(ws + 100663296);   // 24 MB  [Q|K|V]
  unsigned short* Vtb  = (unsigned short*)(ws + 125829120);   // 4 MB   V^T
  unsigned short* Ob   = xb;  // alias: xb dead after QKV gemm

  convert_f32_bf16<<<8192, 256, 0, stream>>>(x, xb, 2097152);
  transpose_f32_bf16<<<dim3(64, 64), 256, 0, stream>>>(wq, wqt, 4096, 4096);
  transpose_f32_bf16<<<dim3(16, 64), 256, 0, stream>>>(wk, wkt, 4096, 1024);
  transpose_f32_bf16<<<dim3(16, 64), 256, 0, stream>>>(wv, wvt, 4096, 1024);
  transpose_f32_bf16<<<dim3(64, 64), 256, 0, stream>>>(wo, wot, 4096, 4096);

  gemm_bt<false><<<dim3(48, 16), 256, 0, stream>>>(xb, wqt, QKVb, 2048, 6144, 4096);

  // Q scale folds softmax 1/sqrt(128) AND log2(e) for exp2-based softmax
  rope_kernel<<<16384, 256, 0, stream>>>(QKVb, cs, 32, 6144, 0, 0.12751743f);
  rope_kernel<<<4096, 256, 0, stream>>>(QKVb, cs, 8, 6144, 4096, 1.0f);

  v_transpose<<<dim3(64, 4, 8), 256, 0, stream>>>(QKVb, Vtb);

  flash_kernel<<<512, 256, 0, stream>>>(QKVb, Vtb, Ob);

  gemm_bt<true><<<dim3(32, 16), 256, 0, stream>>>(Ob, wot, out, 2048, 4096, 4096);
}